// Round 3
// baseline (214.069 us; speedup 1.0000x reference)
//
#include <hip/hip_runtime.h>
#include <hip/hip_bf16.h>

typedef unsigned short u16;
typedef unsigned int u32;
typedef __attribute__((ext_vector_type(8))) short short8;
typedef __attribute__((ext_vector_type(4))) float f32x4;

#define S_LEN 2048
#define D_DIM 1024
#define NH    16
#define DH    64
#define B_SZ  2
#define M_ROWS (B_SZ * S_LEN)   // 4096

// ---------- helpers ----------
__device__ __forceinline__ u16 f2bf(float f) {
  u32 u = __float_as_uint(f);
  u += 0x7FFFu + ((u >> 16) & 1u);   // RNE
  return (u16)(u >> 16);
}
__device__ __forceinline__ float bf2f(u16 u) {
  return __uint_as_float(((u32)u) << 16);
}
__device__ __forceinline__ u32 pack_bf2(float lo, float hi) {
  __hip_bfloat162 p = __float22bfloat162_rn(make_float2(lo, hi));  // v_cvt_pk_bf16_f32
  u32 r;
  __builtin_memcpy(&r, &p, 4);
  return r;
}

__device__ __forceinline__ void gll16(const void* g, void* l) {
  __builtin_amdgcn_global_load_lds((const __attribute__((address_space(1))) u32*)g,
                                   (__attribute__((address_space(3))) u32*)l,
                                   16, 0, 0);
}

// ---------- elementwise conversion fp32 -> bf16 ----------
__global__ __launch_bounds__(256) void cvt_bf16(const float* __restrict__ src,
                                                u16* __restrict__ dst, int n4) {
  int i = blockIdx.x * 256 + threadIdx.x;
  if (i >= n4) return;
  const float4 v = ((const float4*)src)[i];
  u32 lo = (u32)f2bf(v.x) | ((u32)f2bf(v.y) << 16);
  u32 hi = (u32)f2bf(v.z) | ((u32)f2bf(v.w) << 16);
  ((u32*)dst)[2 * i]     = lo;
  ((u32*)dst)[2 * i + 1] = hi;
}

// ---------- RoPE cos/sin table: tab[s][j] for j in [0,32) ----------
__global__ __launch_bounds__(256) void rope_tab(float2* __restrict__ tab) {
  int i = blockIdx.x * 256 + threadIdx.x;   // S_LEN*32 entries
  int s = i >> 5, j = i & 31;
  float inv = exp2f(-(float)j * (13.287712379549449f / 32.f)); // 10000^(-j/32)
  float fr = (float)s * inv;
  tab[i] = make_float2(cosf(fr), sinf(fr));
}

// ---------- shared 128x128-tile GEMM core: C = A[M,K] * W[N,K]^T ----------
__device__ __forceinline__ void gemm128_core(const u16* __restrict__ A,
                                             const u16* __restrict__ W,
                                             int m0, int n0,
                                             u16* As, u16* Bs,
                                             f32x4 acc[4][4]) {
  const int tid  = threadIdx.x;
  const int lane = tid & 63;
  const int wr   = (tid >> 6) >> 1;
  const int wc   = (tid >> 6) & 1;
  const int l15  = lane & 15;
  const int l4   = lane >> 4;

  #pragma unroll
  for (int m = 0; m < 4; ++m)
    #pragma unroll
    for (int n = 0; n < 4; ++n)
      acc[m][n] = (f32x4){0.f, 0.f, 0.f, 0.f};

  for (int kt = 0; kt < D_DIM / 64; ++kt) {
    const int k0 = kt * 64;
    #pragma unroll
    for (int i = 0; i < 4; ++i) {
      int c = tid + i * 256;            // chunk id: 1024 chunks of 16B per tile
      int row = c >> 3, ch = c & 7;
      gll16(A + (size_t)(m0 + row) * D_DIM + k0 + ch * 8, As + c * 8);
      gll16(W + (size_t)(n0 + row) * D_DIM + k0 + ch * 8, Bs + c * 8);
    }
    __syncthreads();
    #pragma unroll
    for (int kk = 0; kk < 2; ++kk) {
      short8 av[4], bv[4];
      #pragma unroll
      for (int m = 0; m < 4; ++m)
        av[m] = *(const short8*)(As + (wr * 64 + m * 16 + l15) * 64 + kk * 32 + l4 * 8);
      #pragma unroll
      for (int n = 0; n < 4; ++n)
        bv[n] = *(const short8*)(Bs + (wc * 64 + n * 16 + l15) * 64 + kk * 32 + l4 * 8);
      #pragma unroll
      for (int m = 0; m < 4; ++m)
        #pragma unroll
        for (int n = 0; n < 4; ++n)
          acc[m][n] = __builtin_amdgcn_mfma_f32_16x16x32_bf16(av[m], bv[n], acc[m][n], 0, 0, 0);
    }
    __syncthreads();
  }
}

// ---------- fused projection: q(+rope, /8), k(+rope), v(->transposed, decay-prescaled), g(silu) ----------
__global__ __launch_bounds__(256) void proj_kernel(
    const u16* __restrict__ xb,
    const u16* __restrict__ wqb, const u16* __restrict__ wkb,
    const u16* __restrict__ wvb, const u16* __restrict__ wgb,
    u16* __restrict__ qb, u16* __restrict__ kb,
    u16* __restrict__ vT, u16* __restrict__ gb,
    const float2* __restrict__ rope)
{
  __shared__ u16 As[128 * 64];
  __shared__ u16 Bs[128 * 64];
  const int z  = blockIdx.z;
  const u16* W = (z == 0) ? wqb : (z == 1) ? wkb : (z == 2) ? wvb : wgb;
  const int m0 = blockIdx.y * 128;
  const int n0 = blockIdx.x * 128;

  f32x4 acc[4][4];
  gemm128_core(xb, W, m0, n0, As, Bs, acc);

  const int lane = threadIdx.x & 63;
  const int wr = (threadIdx.x >> 6) >> 1, wc = (threadIdx.x >> 6) & 1;
  const int l15 = lane & 15, l4 = lane >> 4;
  const int rbase = m0 + wr * 64 + l4 * 4;
  const int cbase = n0 + wc * 64 + l15;

  if (z <= 1) {
    // RoPE; q additionally scaled by 0.125 (exact pow2) to fold the 1/sqrt(Dh)
    u16* dst = z ? kb : qb;
    const float sc = z ? 1.f : 0.125f;
    #pragma unroll
    for (int m = 0; m < 4; ++m)
      #pragma unroll
      for (int n = 0; n < 2; ++n)
        #pragma unroll
        for (int r = 0; r < 4; ++r) {
          const int row = rbase + m * 16 + r;
          const int s = row & (S_LEN - 1);
          const int dh = n * 16 + l15;
          const float2 cs = rope[s * 32 + dh];
          const float x1 = acc[m][n][r];
          const float x2 = acc[m][n + 2][r];
          dst[(size_t)row * D_DIM + cbase + n * 16]       = f2bf((x1 * cs.x - x2 * cs.y) * sc);
          dst[(size_t)row * D_DIM + cbase + (n + 2) * 16] = f2bf((x2 * cs.x + x1 * cs.y) * sc);
        }
  } else if (z == 2) {
    // v stored transposed AND decay-prescaled: vT[(b,h,dh)][t] = gamma_h^(-(t&255)) * v
    #pragma unroll
    for (int n = 0; n < 4; ++n) {
      const int colb = n0 + wc * 64 + n * 16;      // l15 stays within the same head
      const int h = colb >> 6;
      const float nlg = -log2f(1.f - exp2f(-5.f - (float)h));   // > 0
      #pragma unroll
      for (int m = 0; m < 4; ++m)
        #pragma unroll
        for (int r = 0; r < 4; ++r) {
          const int row = rbase + m * 16 + r;
          const int col = colb + l15;
          const int b = row >> 11, s = row & (S_LEN - 1);
          const int dh = col & 63;
          const float f = exp2f((float)(s & 255) * nlg);
          vT[(size_t)((b * NH + h) * DH + dh) * S_LEN + s] = f2bf(acc[m][n][r] * f);
        }
    }
  } else {
    #pragma unroll
    for (int m = 0; m < 4; ++m)
      #pragma unroll
      for (int n = 0; n < 4; ++n)
        #pragma unroll
        for (int r = 0; r < 4; ++r) {
          const int row = rbase + m * 16 + r;
          const int col = cbase + n * 16;
          const float v = acc[m][n][r];
          gb[(size_t)row * D_DIM + col] = f2bf(v / (1.f + __expf(-v)));
        }
  }
}

// ---------- retention v3: swapped-S, decay-folded, zero barriers ----------
// block = (bh, qtile(128 rows), chunk of 4 k-tiles); 4 waves = 4 x 32 q-rows.
// O_chunk[q,:] = gamma^(q-tc) * sum_t mask(S[q,t]) * Vt[t,:]   (Vt prescaled)
__global__ __launch_bounds__(256) void retention_kernel(
    const u16* __restrict__ qb, const u16* __restrict__ kb,
    const u16* __restrict__ vT, float* __restrict__ obf)
{
  __shared__ u16 Ps[4][32 * 64];   // 16 KB, per-wave, XOR-swizzled [q][t]

  const int tid = threadIdx.x, lane = tid & 63, wid = tid >> 6;
  const int l15 = lane & 15, l4 = lane >> 4;

  // ---- job decode: 72 jobs per (b,h) ----
  int job = blockIdx.x;
  const int bh = job / 72; job -= bh * 72;
  const int b = bh >> 4, h = bh & (NH - 1);
  int q = 0, c = job;
  while (true) { int cnt = (q + 2) >> 1; if (c < cnt) break; c -= cnt; ++q; }
  const int s0 = q * 128;
  const int ntile = 2 * q + 2;
  const int tt0 = c * 4;
  const int tt1 = (tt0 + 4 < ntile) ? tt0 + 4 : ntile;
  const int tc = tt0 * 64;          // chunk base, multiple of 256
  const int q0w = s0 + wid * 32;    // this wave's first q-row

  const float lg = log2f(1.f - exp2f(-5.f - (float)h));   // < 0
  const float nlg = -lg;

  // wave-level tile range: causal clamp at the end, decay skip at the front
  int te = tt1;
  while (te > tt0 && (te - 1) * 64 > q0w + 31) --te;
  int ts = tt0;
  while (ts < te && (float)(q0w - (ts * 64 + 63)) * nlg > 30.f) ++ts;
  if (ts >= te) return;   // no barriers anywhere: per-wave exit is safe

  // Q fragments direct from global (q pre-scaled by 1/8): [qfrag][kk]
  short8 qfr[2][2];
  #pragma unroll
  for (int qf = 0; qf < 2; ++qf)
    #pragma unroll
    for (int kk = 0; kk < 2; ++kk)
      qfr[qf][kk] = *(const short8*)(qb + (size_t)(b * S_LEN + q0w + qf * 16 + l15) * D_DIM
                                        + h * DH + kk * 32 + l4 * 8);

  f32x4 acc_o[2][4];
  #pragma unroll
  for (int m = 0; m < 2; ++m)
    #pragma unroll
    for (int n = 0; n < 4; ++n)
      acc_o[m][n] = (f32x4){0.f, 0.f, 0.f, 0.f};

  u16* const psw = &Ps[wid][0];

  for (int tt = ts; tt < te; ++tt) {
    const int t0 = tt * 64;

    // K fragments (A-operand of swapped QK): [kk][tfrag], t on l15
    short8 kf[2][4];
    #pragma unroll
    for (int kk = 0; kk < 2; ++kk)
      #pragma unroll
      for (int tf = 0; tf < 4; ++tf)
        kf[kk][tf] = *(const short8*)(kb + (size_t)(b * S_LEN + t0 + tf * 16 + l15) * D_DIM
                                         + h * DH + kk * 32 + l4 * 8);
    // V~ fragments (B-operand of PV): [kk][dn], d on l15
    short8 vf[2][4];
    #pragma unroll
    for (int kk = 0; kk < 2; ++kk)
      #pragma unroll
      for (int dn = 0; dn < 4; ++dn)
        vf[kk][dn] = *(const short8*)(vT + (size_t)(bh * DH + dn * 16 + l15) * S_LEN
                                         + t0 + kk * 32 + l4 * 8);

    // S^T = mfma(K, Q): lane holds S[q = qf*16+l15][t = t0 + tf*16 + l4*4 + r]
    f32x4 st[4][2];
    #pragma unroll
    for (int tf = 0; tf < 4; ++tf)
      #pragma unroll
      for (int qf = 0; qf < 2; ++qf)
        st[tf][qf] = (f32x4){0.f, 0.f, 0.f, 0.f};
    #pragma unroll
    for (int kk = 0; kk < 2; ++kk)
      #pragma unroll
      for (int tf = 0; tf < 4; ++tf)
        #pragma unroll
        for (int qf = 0; qf < 2; ++qf)
          st[tf][qf] = __builtin_amdgcn_mfma_f32_16x16x32_bf16(kf[kk][tf], qfr[qf][kk], st[tf][qf], 0, 0, 0);

    // mask (diagonal tile only) + pack pairs + swizzled b64 LDS write
    const bool domask = (t0 + 63 > q0w);
    #pragma unroll
    for (int tf = 0; tf < 4; ++tf)
      #pragma unroll
      for (int qf = 0; qf < 2; ++qf) {
        float v0 = st[tf][qf][0], v1 = st[tf][qf][1], v2 = st[tf][qf][2], v3 = st[tf][qf][3];
        if (domask) {
          const int tbase = t0 + tf * 16 + l4 * 4;
          const int qq = q0w + qf * 16 + l15;
          v0 = (tbase + 0 <= qq) ? v0 : 0.f;
          v1 = (tbase + 1 <= qq) ? v1 : 0.f;
          v2 = (tbase + 2 <= qq) ? v2 : 0.f;
          v3 = (tbase + 3 <= qq) ? v3 : 0.f;
        }
        uint2 w = make_uint2(pack_bf2(v0, v1), pack_bf2(v2, v3));
        const int qrow = qf * 16 + l15;
        const int boff = qrow * 128 + ((tf * 32 + l4 * 8) ^ ((l15 & 7) << 4));
        *(uint2*)((char*)psw + boff) = w;
      }

    // O += P~ V~  (same-wave LDS RAW: compiler inserts lgkmcnt, no barrier needed)
    #pragma unroll
    for (int kk = 0; kk < 2; ++kk) {
      short8 pa[2];
      #pragma unroll
      for (int qf = 0; qf < 2; ++qf) {
        const int qrow = qf * 16 + l15;
        const int boff = qrow * 128 + ((kk * 64 + l4 * 16) ^ ((l15 & 7) << 4));
        pa[qf] = *(const short8*)((const char*)psw + boff);
      }
      #pragma unroll
      for (int qf = 0; qf < 2; ++qf)
        #pragma unroll
        for (int dn = 0; dn < 4; ++dn)
          acc_o[qf][dn] = __builtin_amdgcn_mfma_f32_16x16x32_bf16(pa[qf], vf[kk][dn], acc_o[qf][dn], 0, 0, 0);
    }
  }

  // epilogue: row scale gamma^(q - tc), then partial-O accumulate
  #pragma unroll
  for (int qf = 0; qf < 2; ++qf)
    #pragma unroll
    for (int r = 0; r < 4; ++r) {
      const int qq = q0w + qf * 16 + l4 * 4 + r;
      const float sc = exp2f((float)(qq - tc) * lg);
      #pragma unroll
      for (int dn = 0; dn < 4; ++dn)
        atomicAdd(&obf[(size_t)(b * S_LEN + qq) * D_DIM + h * DH + dn * 16 + l15],
                  acc_o[qf][dn][r] * sc);
    }
}

// ---------- fuse: ob = bf16(obf * g) ----------
__global__ __launch_bounds__(256) void fuse_og(const float* __restrict__ obf,
                                               const u16* __restrict__ gb,
                                               u16* __restrict__ ob, int n8) {
  int i = blockIdx.x * 256 + threadIdx.x;
  if (i >= n8) return;
  const float4 a0 = ((const float4*)obf)[2 * i];
  const float4 a1 = ((const float4*)obf)[2 * i + 1];
  const short8 g = ((const short8*)gb)[i];
  float av[8] = {a0.x, a0.y, a0.z, a0.w, a1.x, a1.y, a1.z, a1.w};
  short8 out;
  #pragma unroll
  for (int j = 0; j < 8; ++j)
    out[j] = (short)f2bf(av[j] * bf2f((u16)g[j]));
  ((short8*)ob)[i] = out;
}

// ---------- final GEMM: out = (O .* g) @ wo^T, fp32 output ----------
__global__ __launch_bounds__(256) void final_kernel(
    const u16* __restrict__ ob, const u16* __restrict__ wob,
    float* __restrict__ out)
{
  __shared__ u16 As[128 * 64];
  __shared__ u16 Bs[128 * 64];
  const int m0 = blockIdx.y * 128, n0 = blockIdx.x * 128;
  f32x4 acc[4][4];
  gemm128_core(ob, wob, m0, n0, As, Bs, acc);

  const int lane = threadIdx.x & 63;
  const int wr = (threadIdx.x >> 6) >> 1, wc = (threadIdx.x >> 6) & 1;
  const int rbase = m0 + wr * 64 + (lane >> 4) * 4;
  const int cbase = n0 + wc * 64 + (lane & 15);
  #pragma unroll
  for (int m = 0; m < 4; ++m)
    #pragma unroll
    for (int n = 0; n < 4; ++n)
      #pragma unroll
      for (int r = 0; r < 4; ++r)
        out[(size_t)(rbase + m * 16 + r) * D_DIM + cbase + n * 16] = acc[m][n][r];
}

extern "C" void kernel_launch(void* const* d_in, const int* in_sizes, int n_in,
                              void* d_out, int out_size, void* d_ws, size_t ws_size,
                              hipStream_t stream) {
  (void)in_sizes; (void)n_in; (void)out_size; (void)ws_size;
  const float* x  = (const float*)d_in[0];
  const float* wq = (const float*)d_in[1];
  const float* wk = (const float*)d_in[2];
  const float* wv = (const float*)d_in[3];
  const float* wg = (const float*)d_in[4];
  const float* wo = (const float*)d_in[5];
  float* out = (float*)d_out;

  char* ws = (char*)d_ws;
  const size_t SZ_X = (size_t)M_ROWS * D_DIM * 2;   // 8 MB
  const size_t SZ_W = (size_t)D_DIM * D_DIM * 2;    // 2 MB
  u16* xb  = (u16*)(ws);
  u16* wqb = (u16*)(ws + SZ_X);
  u16* wkb = (u16*)(ws + SZ_X + 1 * SZ_W);
  u16* wvb = (u16*)(ws + SZ_X + 2 * SZ_W);
  u16* wgb = (u16*)(ws + SZ_X + 3 * SZ_W);
  u16* wob = (u16*)(ws + SZ_X + 4 * SZ_W);
  u16* qb  = (u16*)(ws + 1 * SZ_X + 5 * SZ_W);
  u16* kb  = (u16*)(ws + 2 * SZ_X + 5 * SZ_W);
  u16* vT  = (u16*)(ws + 3 * SZ_X + 5 * SZ_W);
  u16* gb  = (u16*)(ws + 4 * SZ_X + 5 * SZ_W);
  u16* ob  = (u16*)(ws + 5 * SZ_X + 5 * SZ_W);
  float2* rope = (float2*)(ws + 6 * SZ_X + 5 * SZ_W);
  // obf (fp32, 16MB) aliases xb..wgb — dead after proj_kernel. wob starts at 16MB.
  float* obf = (float*)(ws);

  const int nx4 = M_ROWS * D_DIM / 4;
  const int nw4 = D_DIM * D_DIM / 4;
  cvt_bf16<<<nx4 / 256, 256, 0, stream>>>(x,  xb,  nx4);
  cvt_bf16<<<nw4 / 256, 256, 0, stream>>>(wq, wqb, nw4);
  cvt_bf16<<<nw4 / 256, 256, 0, stream>>>(wk, wkb, nw4);
  cvt_bf16<<<nw4 / 256, 256, 0, stream>>>(wv, wvb, nw4);
  cvt_bf16<<<nw4 / 256, 256, 0, stream>>>(wg, wgb, nw4);
  cvt_bf16<<<nw4 / 256, 256, 0, stream>>>(wo, wob, nw4);
  rope_tab<<<(S_LEN * 32) / 256, 256, 0, stream>>>(rope);

  proj_kernel<<<dim3(D_DIM / 128, M_ROWS / 128, 4), 256, 0, stream>>>(
      xb, wqb, wkb, wvb, wgb, qb, kb, vT, gb, rope);

  hipMemsetAsync(obf, 0, (size_t)M_ROWS * D_DIM * sizeof(float), stream);

  retention_kernel<<<dim3(72 * B_SZ * NH), 256, 0, stream>>>(qb, kb, vT, obf);

  fuse_og<<<(M_ROWS * D_DIM / 8 + 255) / 256, 256, 0, stream>>>(
      obf, gb, ob, M_ROWS * D_DIM / 8);

  final_kernel<<<dim3(D_DIM / 128, M_ROWS / 128), 256, 0, stream>>>(ob, wob, out);
}

// Round 4
// 145.991 us; speedup vs baseline: 1.4663x; 1.4663x over previous
//
#include <hip/hip_runtime.h>
#include <hip/hip_bf16.h>

typedef unsigned short u16;
typedef unsigned int u32;
typedef __attribute__((ext_vector_type(8))) short short8;
typedef __attribute__((ext_vector_type(4))) float f32x4;

#define S_LEN 2048
#define D_DIM 1024
#define NH    16
#define DH    64
#define B_SZ  2
#define M_ROWS (B_SZ * S_LEN)   // 4096
#define NCHUNK (S_LEN / 64)     // 32 chunks of 64 rows

// ---------- helpers ----------
__device__ __forceinline__ u16 f2bf(float f) {
  u32 u = __float_as_uint(f);
  u += 0x7FFFu + ((u >> 16) & 1u);   // RNE
  return (u16)(u >> 16);
}
__device__ __forceinline__ float bf2f(u16 u) {
  return __uint_as_float(((u32)u) << 16);
}
__device__ __forceinline__ u32 pack_bf2(float lo, float hi) {
  __hip_bfloat162 p = __float22bfloat162_rn(make_float2(lo, hi));  // v_cvt_pk_bf16_f32
  u32 r;
  __builtin_memcpy(&r, &p, 4);
  return r;
}

__device__ __forceinline__ void gll16(const void* g, void* l) {
  __builtin_amdgcn_global_load_lds((const __attribute__((address_space(1))) u32*)g,
                                   (__attribute__((address_space(3))) u32*)l,
                                   16, 0, 0);
}

// ---------- elementwise conversion fp32 -> bf16 ----------
__global__ __launch_bounds__(256) void cvt_bf16(const float* __restrict__ src,
                                                u16* __restrict__ dst, int n4) {
  int i = blockIdx.x * 256 + threadIdx.x;
  if (i >= n4) return;
  const float4 v = ((const float4*)src)[i];
  u32 lo = (u32)f2bf(v.x) | ((u32)f2bf(v.y) << 16);
  u32 hi = (u32)f2bf(v.z) | ((u32)f2bf(v.w) << 16);
  ((u32*)dst)[2 * i]     = lo;
  ((u32*)dst)[2 * i + 1] = hi;
}

// ---------- RoPE cos/sin table: tab[s][j] for j in [0,32) ----------
__global__ __launch_bounds__(256) void rope_tab(float2* __restrict__ tab) {
  int i = blockIdx.x * 256 + threadIdx.x;   // S_LEN*32 entries
  int s = i >> 5, j = i & 31;
  float inv = exp2f(-(float)j * (13.287712379549449f / 32.f)); // 10000^(-j/32)
  float fr = (float)s * inv;
  tab[i] = make_float2(cosf(fr), sinf(fr));
}

// ---------- shared 128x128-tile GEMM core: C = A[M,K] * W[N,K]^T ----------
__device__ __forceinline__ void gemm128_core(const u16* __restrict__ A,
                                             const u16* __restrict__ W,
                                             int m0, int n0,
                                             u16* As, u16* Bs,
                                             f32x4 acc[4][4]) {
  const int tid  = threadIdx.x;
  const int lane = tid & 63;
  const int wr   = (tid >> 6) >> 1;
  const int wc   = (tid >> 6) & 1;
  const int l15  = lane & 15;
  const int l4   = lane >> 4;

  #pragma unroll
  for (int m = 0; m < 4; ++m)
    #pragma unroll
    for (int n = 0; n < 4; ++n)
      acc[m][n] = (f32x4){0.f, 0.f, 0.f, 0.f};

  for (int kt = 0; kt < D_DIM / 64; ++kt) {
    const int k0 = kt * 64;
    #pragma unroll
    for (int i = 0; i < 4; ++i) {
      int c = tid + i * 256;            // chunk id: 1024 chunks of 16B per tile
      int row = c >> 3, ch = c & 7;
      gll16(A + (size_t)(m0 + row) * D_DIM + k0 + ch * 8, As + c * 8);
      gll16(W + (size_t)(n0 + row) * D_DIM + k0 + ch * 8, Bs + c * 8);
    }
    __syncthreads();
    #pragma unroll
    for (int kk = 0; kk < 2; ++kk) {
      short8 av[4], bv[4];
      #pragma unroll
      for (int m = 0; m < 4; ++m)
        av[m] = *(const short8*)(As + (wr * 64 + m * 16 + l15) * 64 + kk * 32 + l4 * 8);
      #pragma unroll
      for (int n = 0; n < 4; ++n)
        bv[n] = *(const short8*)(Bs + (wc * 64 + n * 16 + l15) * 64 + kk * 32 + l4 * 8);
      #pragma unroll
      for (int m = 0; m < 4; ++m)
        #pragma unroll
        for (int n = 0; n < 4; ++n)
          acc[m][n] = __builtin_amdgcn_mfma_f32_16x16x32_bf16(av[m], bv[n], acc[m][n], 0, 0, 0);
    }
    __syncthreads();
  }
}

// ---------- fused projection ----------
// z=0: qb = 0.125*gamma^(s&63) * rope(x@wq^T)      (Q-tilde)
// z=1: kb = gamma^(-(s&63)) * rope(x@wk^T), plus kT = transposed copy  (K-hat)
// z=2: vT = transpose(x@wv^T)
// z=3: gb = silu(x@wg^T)
__global__ __launch_bounds__(256) void proj_kernel(
    const u16* __restrict__ xb,
    const u16* __restrict__ wqb, const u16* __restrict__ wkb,
    const u16* __restrict__ wvb, const u16* __restrict__ wgb,
    u16* __restrict__ qb, u16* __restrict__ kb, u16* __restrict__ kT,
    u16* __restrict__ vT, u16* __restrict__ gb,
    const float2* __restrict__ rope)
{
  __shared__ u16 As[128 * 64];
  __shared__ u16 Bs[128 * 64];
  const int z  = blockIdx.z;
  const u16* W = (z == 0) ? wqb : (z == 1) ? wkb : (z == 2) ? wvb : wgb;
  const int m0 = blockIdx.y * 128;
  const int n0 = blockIdx.x * 128;

  f32x4 acc[4][4];
  gemm128_core(xb, W, m0, n0, As, Bs, acc);

  const int lane = threadIdx.x & 63;
  const int wr = (threadIdx.x >> 6) >> 1, wc = (threadIdx.x >> 6) & 1;
  const int l15 = lane & 15, l4 = lane >> 4;
  const int rbase = m0 + wr * 64 + l4 * 4;
  const int cbase = n0 + wc * 64 + l15;
  const int hh = (n0 + wc * 64) >> 6;    // wave's 64-col block = exactly one head
  const float lgh = log2f(1.f - exp2f(-5.f - (float)hh));   // log2(gamma_h) < 0

  if (z <= 1) {
    u16* dst = z ? kb : qb;
    const float slg  = z ? -lgh : lgh;
    const float base = z ? 1.f : 0.125f;
    #pragma unroll
    for (int m = 0; m < 4; ++m)
      #pragma unroll
      for (int r = 0; r < 4; ++r) {
        const int row = rbase + m * 16 + r;
        const int s = row & (S_LEN - 1);
        const float sc = base * exp2f((float)(s & 63) * slg);
        #pragma unroll
        for (int n = 0; n < 2; ++n) {
          const int dh0 = n * 16 + l15;              // 0..31 within head
          const float2 cs = rope[s * 32 + dh0];
          const float x1 = acc[m][n][r];
          const float x2 = acc[m][n + 2][r];
          const float o1 = (x1 * cs.x - x2 * cs.y) * sc;
          const float o2 = (x2 * cs.x + x1 * cs.y) * sc;
          dst[(size_t)row * D_DIM + cbase + n * 16]       = f2bf(o1);
          dst[(size_t)row * D_DIM + cbase + (n + 2) * 16] = f2bf(o2);
          if (z == 1) {
            const int bb = row >> 11;
            kT[(size_t)((bb * NH + hh) * DH + dh0) * S_LEN + s]      = f2bf(o1);
            kT[(size_t)((bb * NH + hh) * DH + dh0 + 32) * S_LEN + s] = f2bf(o2);
          }
        }
      }
  } else if (z == 2) {
    // v stored transposed: vT[(b,h,dh)][s]
    #pragma unroll
    for (int m = 0; m < 4; ++m)
      #pragma unroll
      for (int n = 0; n < 4; ++n)
        #pragma unroll
        for (int r = 0; r < 4; ++r) {
          const int row = rbase + m * 16 + r;
          const int bb = row >> 11, s = row & (S_LEN - 1);
          const int dh = n * 16 + l15;   // 0..63 within head
          vT[(size_t)((bb * NH + hh) * DH + dh) * S_LEN + s] = f2bf(acc[m][n][r]);
        }
  } else {
    #pragma unroll
    for (int m = 0; m < 4; ++m)
      #pragma unroll
      for (int n = 0; n < 4; ++n)
        #pragma unroll
        for (int r = 0; r < 4; ++r) {
          const int row = rbase + m * 16 + r;
          const int col = cbase + n * 16;
          const float v = acc[m][n][r];
          gb[(size_t)row * D_DIM + col] = f2bf(v / (1.f + __expf(-v)));
        }
  }
}

// ---------- phase A: per-chunk outer product  At[bh][c][d2][d1] = (K-hat^T V)^T ----------
// At[d2][d1] = sum_t V[t,d2] * K-hat[t,d1]; block = (bh, c), wave w owns d2-block w*16.
__global__ __launch_bounds__(256) void chunk_accum(
    const u16* __restrict__ kT, const u16* __restrict__ vT,
    u16* __restrict__ At)
{
  const int tid = threadIdx.x, lane = tid & 63, w = tid >> 6;
  const int l15 = lane & 15, l4 = lane >> 4;
  const int bh = blockIdx.x >> 5, c = blockIdx.x & 31;

  short8 a[2], bfr[2][4];
  #pragma unroll
  for (int kk = 0; kk < 2; ++kk) {
    a[kk] = *(const short8*)(vT + (size_t)(bh * DH + w * 16 + l15) * S_LEN + c * 64 + kk * 32 + l4 * 8);
    #pragma unroll
    for (int n = 0; n < 4; ++n)
      bfr[kk][n] = *(const short8*)(kT + (size_t)(bh * DH + n * 16 + l15) * S_LEN + c * 64 + kk * 32 + l4 * 8);
  }
  f32x4 acc[4];
  #pragma unroll
  for (int n = 0; n < 4; ++n) acc[n] = (f32x4){0.f, 0.f, 0.f, 0.f};
  #pragma unroll
  for (int kk = 0; kk < 2; ++kk)
    #pragma unroll
    for (int n = 0; n < 4; ++n)
      acc[n] = __builtin_amdgcn_mfma_f32_16x16x32_bf16(a[kk], bfr[kk][n], acc[n], 0, 0, 0);

  u16* dst = At + ((size_t)(bh * NCHUNK + c)) * 4096;
  #pragma unroll
  for (int n = 0; n < 4; ++n)
    #pragma unroll
    for (int r = 0; r < 4; ++r)
      dst[(w * 16 + l4 * 4 + r) * 64 + n * 16 + l15] = f2bf(acc[n][r]);
}

// ---------- phase B: elementwise scan over chunks ----------
// St[bh][c] = sum_{c'<c} (gamma^64)^(c-c') * At[bh][c']   (recurrence s = gC*(s+a))
__global__ __launch_bounds__(256) void chunk_scan(
    const u16* __restrict__ At, u16* __restrict__ St)
{
  const int gid = blockIdx.x * 256 + threadIdx.x;   // 32 bh * 4096 elems
  const int bh = gid >> 12, e = gid & 4095;
  const int h = bh & (NH - 1);
  const float lg = log2f(1.f - exp2f(-5.f - (float)h));
  const float gC = exp2f(64.f * lg);
  const u16* src = At + (size_t)bh * NCHUNK * 4096 + e;
  u16* dst = St + (size_t)bh * NCHUNK * 4096 + e;
  float s = 0.f;
  for (int c = 0; c < NCHUNK; ++c) {
    const float a = bf2f(src[(size_t)c * 4096]);
    dst[(size_t)c * 4096] = f2bf(s);
    s = gC * (s + a);
  }
}

// ---------- phase C: O = (masked Q~K^^T) V + Q~ State, fused * g ----------
// block = (bh, c); wave w owns q-rows [c*64 + w*16, +16).
__global__ __launch_bounds__(256) void chunk_out(
    const u16* __restrict__ qb, const u16* __restrict__ kb,
    const u16* __restrict__ vT, const u16* __restrict__ St,
    const u16* __restrict__ gb, u16* __restrict__ ob)
{
  __shared__ u16 Ps[4][16 * 64];   // 2 KB per wave, XOR-swizzled

  const int tid = threadIdx.x, lane = tid & 63, w = tid >> 6;
  const int l15 = lane & 15, l4 = lane >> 4;
  const int bh = blockIdx.x >> 5, c = blockIdx.x & 31;
  const int b = bh >> 4, h = bh & (NH - 1);
  const int q0 = c * 64 + w * 16;   // first q row (within batch) of this wave

  // operand fragments (all row=l15, k=l4*8 layout)
  short8 qfr[2], kf[2][4], vf[2][4], sf[2][4];
  #pragma unroll
  for (int kk = 0; kk < 2; ++kk) {
    qfr[kk] = *(const short8*)(qb + (size_t)(b * S_LEN + q0 + l15) * D_DIM + h * DH + kk * 32 + l4 * 8);
    #pragma unroll
    for (int t = 0; t < 4; ++t)
      kf[kk][t] = *(const short8*)(kb + (size_t)(b * S_LEN + c * 64 + t * 16 + l15) * D_DIM + h * DH + kk * 32 + l4 * 8);
    #pragma unroll
    for (int n = 0; n < 4; ++n) {
      vf[kk][n] = *(const short8*)(vT + (size_t)(bh * DH + n * 16 + l15) * S_LEN + c * 64 + kk * 32 + l4 * 8);
      sf[kk][n] = *(const short8*)(St + ((size_t)(bh * NCHUNK + c)) * 4096 + (n * 16 + l15) * 64 + kk * 32 + l4 * 8);
    }
  }

  // S^T = mfma(K^, Q~): lane holds S[q'=w*16+l15][t'=tf*16+l4*4+r]
  f32x4 st[4];
  #pragma unroll
  for (int tf = 0; tf < 4; ++tf) st[tf] = (f32x4){0.f, 0.f, 0.f, 0.f};
  #pragma unroll
  for (int kk = 0; kk < 2; ++kk)
    #pragma unroll
    for (int tf = 0; tf < 4; ++tf)
      st[tf] = __builtin_amdgcn_mfma_f32_16x16x32_bf16(kf[kk][tf], qfr[kk], st[tf], 0, 0, 0);

  // cross term first: acc = Q~ StateT  (rows q on l4*4+r, cols dh on l15)
  f32x4 acc[4];
  #pragma unroll
  for (int n = 0; n < 4; ++n) acc[n] = (f32x4){0.f, 0.f, 0.f, 0.f};
  #pragma unroll
  for (int kk = 0; kk < 2; ++kk)
    #pragma unroll
    for (int n = 0; n < 4; ++n)
      acc[n] = __builtin_amdgcn_mfma_f32_16x16x32_bf16(qfr[kk], sf[kk][n], acc[n], 0, 0, 0);

  // mask (t' <= q'), pack, swizzled per-wave LDS write
  u16* const psw = &Ps[w][0];
  const int qq = w * 16 + l15;   // chunk-local q'
  #pragma unroll
  for (int tf = 0; tf < 4; ++tf) {
    const int tb = tf * 16 + l4 * 4;
    const float v0 = (tb + 0 <= qq) ? st[tf][0] : 0.f;
    const float v1 = (tb + 1 <= qq) ? st[tf][1] : 0.f;
    const float v2 = (tb + 2 <= qq) ? st[tf][2] : 0.f;
    const float v3 = (tb + 3 <= qq) ? st[tf][3] : 0.f;
    const uint2 u = make_uint2(pack_bf2(v0, v1), pack_bf2(v2, v3));
    const int boff = l15 * 128 + ((tf * 32 + l4 * 8) ^ ((l15 & 7) << 4));
    *(uint2*)((char*)psw + boff) = u;
  }

  // O += P V  (same-wave LDS RAW; compiler inserts lgkmcnt)
  #pragma unroll
  for (int kk = 0; kk < 2; ++kk) {
    const int boff = l15 * 128 + ((kk * 64 + l4 * 16) ^ ((l15 & 7) << 4));
    const short8 pa = *(const short8*)((const char*)psw + boff);
    #pragma unroll
    for (int n = 0; n < 4; ++n)
      acc[n] = __builtin_amdgcn_mfma_f32_16x16x32_bf16(pa, vf[kk][n], acc[n], 0, 0, 0);
  }

  // epilogue: ob = bf16(acc * g), each element written exactly once
  #pragma unroll
  for (int n = 0; n < 4; ++n)
    #pragma unroll
    for (int r = 0; r < 4; ++r) {
      const size_t idx = (size_t)(b * S_LEN + q0 + l4 * 4 + r) * D_DIM + h * DH + n * 16 + l15;
      ob[idx] = f2bf(acc[n][r] * bf2f(gb[idx]));
    }
}

// ---------- final GEMM: out = (O .* g) @ wo^T, fp32 output ----------
__global__ __launch_bounds__(256) void final_kernel(
    const u16* __restrict__ ob, const u16* __restrict__ wob,
    float* __restrict__ out)
{
  __shared__ u16 As[128 * 64];
  __shared__ u16 Bs[128 * 64];
  const int m0 = blockIdx.y * 128, n0 = blockIdx.x * 128;
  f32x4 acc[4][4];
  gemm128_core(ob, wob, m0, n0, As, Bs, acc);

  const int lane = threadIdx.x & 63;
  const int wr = (threadIdx.x >> 6) >> 1, wc = (threadIdx.x >> 6) & 1;
  const int rbase = m0 + wr * 64 + (lane >> 4) * 4;
  const int cbase = n0 + wc * 64 + (lane & 15);
  #pragma unroll
  for (int m = 0; m < 4; ++m)
    #pragma unroll
    for (int n = 0; n < 4; ++n)
      #pragma unroll
      for (int r = 0; r < 4; ++r)
        out[(size_t)(rbase + m * 16 + r) * D_DIM + cbase + n * 16] = acc[m][n][r];
}

extern "C" void kernel_launch(void* const* d_in, const int* in_sizes, int n_in,
                              void* d_out, int out_size, void* d_ws, size_t ws_size,
                              hipStream_t stream) {
  (void)in_sizes; (void)n_in; (void)out_size; (void)ws_size;
  const float* x  = (const float*)d_in[0];
  const float* wq = (const float*)d_in[1];
  const float* wk = (const float*)d_in[2];
  const float* wv = (const float*)d_in[3];
  const float* wg = (const float*)d_in[4];
  const float* wo = (const float*)d_in[5];
  float* out = (float*)d_out;

  char* ws = (char*)d_ws;
  const size_t SZ_X = (size_t)M_ROWS * D_DIM * 2;   // 8 MB
  const size_t SZ_W = (size_t)D_DIM * D_DIM * 2;    // 2 MB
  // [0..8)   xb            -> St  (bf16 state, dead-x alias, used after proj)
  // [8..16)  wqb..wgb      -> At  (bf16 chunk products, dead-weights alias)
  // [16..18) wob           (live until final_kernel)
  // [18..26) qb  [26..34) kb  [34..42) vT  [42..50) gb
  // [50..58) kT            -> ob  (kT dead after chunk_accum; ob written by chunk_out)
  // [58..58.5) rope
  u16* xb  = (u16*)(ws);
  u16* wqb = (u16*)(ws + SZ_X);
  u16* wkb = (u16*)(ws + SZ_X + 1 * SZ_W);
  u16* wvb = (u16*)(ws + SZ_X + 2 * SZ_W);
  u16* wgb = (u16*)(ws + SZ_X + 3 * SZ_W);
  u16* wob = (u16*)(ws + SZ_X + 4 * SZ_W);
  u16* qb  = (u16*)(ws + 1 * SZ_X + 5 * SZ_W);
  u16* kb  = (u16*)(ws + 2 * SZ_X + 5 * SZ_W);
  u16* vT  = (u16*)(ws + 3 * SZ_X + 5 * SZ_W);
  u16* gb  = (u16*)(ws + 4 * SZ_X + 5 * SZ_W);
  u16* kT  = (u16*)(ws + 5 * SZ_X + 5 * SZ_W);
  u16* ob  = kT;                                    // alias: kT dead after chunk_accum
  float2* rope = (float2*)(ws + 6 * SZ_X + 5 * SZ_W);
  u16* St  = (u16*)(ws);                            // alias: xb dead after proj
  u16* At  = (u16*)(ws + SZ_X);                     // alias: wqb..wgb dead after proj

  const int nx4 = M_ROWS * D_DIM / 4;
  const int nw4 = D_DIM * D_DIM / 4;
  cvt_bf16<<<nx4 / 256, 256, 0, stream>>>(x,  xb,  nx4);
  cvt_bf16<<<nw4 / 256, 256, 0, stream>>>(wq, wqb, nw4);
  cvt_bf16<<<nw4 / 256, 256, 0, stream>>>(wk, wkb, nw4);
  cvt_bf16<<<nw4 / 256, 256, 0, stream>>>(wv, wvb, nw4);
  cvt_bf16<<<nw4 / 256, 256, 0, stream>>>(wg, wgb, nw4);
  cvt_bf16<<<nw4 / 256, 256, 0, stream>>>(wo, wob, nw4);
  rope_tab<<<(S_LEN * 32) / 256, 256, 0, stream>>>(rope);

  proj_kernel<<<dim3(D_DIM / 128, M_ROWS / 128, 4), 256, 0, stream>>>(
      xb, wqb, wkb, wvb, wgb, qb, kb, kT, vT, gb, rope);

  chunk_accum<<<dim3(B_SZ * NH * NCHUNK), 256, 0, stream>>>(kT, vT, At);
  chunk_scan<<<dim3(B_SZ * NH * 4096 / 256), 256, 0, stream>>>(At, St);
  chunk_out<<<dim3(B_SZ * NH * NCHUNK), 256, 0, stream>>>(qb, kb, vT, St, gb, ob);

  final_kernel<<<dim3(D_DIM / 128, M_ROWS / 128), 256, 0, stream>>>(ob, wob, out);
}

// Round 5
// 110.172 us; speedup vs baseline: 1.9430x; 1.3251x over previous
//
#include <hip/hip_runtime.h>
#include <hip/hip_bf16.h>

typedef unsigned short u16;
typedef unsigned int u32;
typedef __attribute__((ext_vector_type(8))) short short8;
typedef __attribute__((ext_vector_type(4))) float f32x4;

#define S_LEN 2048
#define D_DIM 1024
#define NH    16
#define DH    64
#define B_SZ  2
#define M_ROWS (B_SZ * S_LEN)   // 4096
#define NCHUNK (S_LEN / 64)     // 32 chunks of 64 rows

// ---------- helpers ----------
__device__ __forceinline__ u16 f2bf(float f) {
  u32 u = __float_as_uint(f);
  u += 0x7FFFu + ((u >> 16) & 1u);   // RNE
  return (u16)(u >> 16);
}
__device__ __forceinline__ float bf2f(u16 u) {
  return __uint_as_float(((u32)u) << 16);
}
__device__ __forceinline__ u32 pack_bf2(float lo, float hi) {
  __hip_bfloat162 p = __float22bfloat162_rn(make_float2(lo, hi));  // v_cvt_pk_bf16_f32
  u32 r;
  __builtin_memcpy(&r, &p, 4);
  return r;
}

__device__ __forceinline__ void gll16(const void* g, void* l) {
  __builtin_amdgcn_global_load_lds((const __attribute__((address_space(1))) u32*)g,
                                   (__attribute__((address_space(3))) u32*)l,
                                   16, 0, 0);
}

// ---------- elementwise conversion fp32 -> bf16 ----------
__global__ __launch_bounds__(256) void cvt_bf16(const float* __restrict__ src,
                                                u16* __restrict__ dst, int n4) {
  int i = blockIdx.x * 256 + threadIdx.x;
  if (i >= n4) return;
  const float4 v = ((const float4*)src)[i];
  u32 lo = (u32)f2bf(v.x) | ((u32)f2bf(v.y) << 16);
  u32 hi = (u32)f2bf(v.z) | ((u32)f2bf(v.w) << 16);
  ((u32*)dst)[2 * i]     = lo;
  ((u32*)dst)[2 * i + 1] = hi;
}

// all 5 weights -> one contiguous bf16 buffer (wq,wk,wv,wg,wo)
__global__ __launch_bounds__(256) void cvt_w5(const float* __restrict__ wq,
                                              const float* __restrict__ wk,
                                              const float* __restrict__ wv,
                                              const float* __restrict__ wg,
                                              const float* __restrict__ wo,
                                              u16* __restrict__ dst) {
  const int seg = blockIdx.y;
  const float* src = seg == 0 ? wq : seg == 1 ? wk : seg == 2 ? wv : seg == 3 ? wg : wo;
  const int i = blockIdx.x * 256 + threadIdx.x;     // < 1024*1024/4
  const float4 v = ((const float4*)src)[i];
  u32* d = (u32*)(dst + (size_t)seg * D_DIM * D_DIM);
  d[2 * i]     = (u32)f2bf(v.x) | ((u32)f2bf(v.y) << 16);
  d[2 * i + 1] = (u32)f2bf(v.z) | ((u32)f2bf(v.w) << 16);
}

// ---------- RoPE cos/sin table: tab[s][j] for j in [0,32) ----------
__global__ __launch_bounds__(256) void rope_tab(float2* __restrict__ tab) {
  int i = blockIdx.x * 256 + threadIdx.x;   // S_LEN*32 entries
  int s = i >> 5, j = i & 31;
  float inv = exp2f(-(float)j * (13.287712379549449f / 32.f)); // 10000^(-j/32)
  float fr = (float)s * inv;
  tab[i] = make_float2(cosf(fr), sinf(fr));
}

// ---------- deep-pipelined GEMM core: C = A[M,1024] * W[N,1024]^T ----------
// BK=32, ring of 4 LDS slots, staging 2 K-tiles ahead, counted vmcnt(4),
// one raw barrier per K-step, setprio around the MFMA cluster.
// Frag reads are 64-lane contiguous 1024B => zero LDS bank conflicts.
template<int BM, int BN, int WPM, int WPN>
__device__ __forceinline__ void gemm_bk32(const u16* __restrict__ A,
                                          const u16* __restrict__ W,
                                          const int m0, const int n0,
                                          u16* lds,
                                          f32x4 (&acc)[BM / (WPM * 16)][BN / (WPN * 16)])
{
  constexpr int T   = WPM * WPN * 64;      // threads
  constexpr int MR  = BM / (WPM * 16);
  constexpr int NR  = BN / (WPN * 16);
  constexpr int ALD = BM * 32;             // A elems per slot
  constexpr int BLD = BN * 32;
  constexpr int BUF = ALD + BLD;           // elems per ring slot
  constexpr int NK  = D_DIM / 32;          // 32 K-steps

  const int tid  = threadIdx.x;
  const int lane = tid & 63, wid = tid >> 6;
  const int wm = wid / WPN, wn = wid % WPN;
  const int l15 = lane & 15, l4 = lane >> 4;

  #pragma unroll
  for (int m = 0; m < MR; ++m)
    #pragma unroll
    for (int n = 0; n < NR; ++n)
      acc[m][n] = (f32x4){0.f, 0.f, 0.f, 0.f};

  auto stage = [&](int kt) {
    const int k0 = kt * 32;
    u16* la = lds + (kt & 3) * BUF;
    u16* lb = la + ALD;
    #pragma unroll
    for (int j = 0; j < BM * 4 / T; ++j) {          // 2 chunks of A (16B each)
      const int c = tid + j * T;
      gll16(A + (size_t)(m0 + (c >> 2)) * D_DIM + k0 + (c & 3) * 8, la + c * 8);
    }
    #pragma unroll
    for (int j = 0; j < BN * 4 / T; ++j) {          // 2 chunks of B
      const int c = tid + j * T;
      gll16(W + (size_t)(n0 + (c >> 2)) * D_DIM + k0 + (c & 3) * 8, lb + c * 8);
    }
  };

  // prologue: 2 tiles in flight, wait only the first
  stage(0);
  stage(1);
  asm volatile("s_waitcnt vmcnt(4)" ::: "memory");
  __builtin_amdgcn_s_barrier();
  __builtin_amdgcn_sched_barrier(0);

  for (int i = 0; i < NK; ++i) {
    if (i + 2 < NK) stage(i + 2);                   // issue-early, 2 tiles ahead
    const u16* la = lds + (i & 3) * BUF + (wm * (BM / WPM) + l15) * 32 + l4 * 8;
    const u16* lb = lds + (i & 3) * BUF + ALD + (wn * (BN / WPN) + l15) * 32 + l4 * 8;
    short8 av[MR], bv[NR];
    #pragma unroll
    for (int m = 0; m < MR; ++m) av[m] = *(const short8*)(la + m * 16 * 32);
    #pragma unroll
    for (int n = 0; n < NR; ++n) bv[n] = *(const short8*)(lb + n * 16 * 32);
    __builtin_amdgcn_s_setprio(1);
    #pragma unroll
    for (int m = 0; m < MR; ++m)
      #pragma unroll
      for (int n = 0; n < NR; ++n)
        acc[m][n] = __builtin_amdgcn_mfma_f32_16x16x32_bf16(av[m], bv[n], acc[m][n], 0, 0, 0);
    __builtin_amdgcn_s_setprio(0);
    // counted wait: keep the 4 just-issued loads in flight, require tile i+1 done
    if (i + 2 < NK) asm volatile("s_waitcnt vmcnt(4)" ::: "memory");
    else            asm volatile("s_waitcnt vmcnt(0)" ::: "memory");
    __builtin_amdgcn_s_barrier();
    __builtin_amdgcn_sched_barrier(0);
  }
}

// ---------- fused projection: ONE GEMM over concat weights [4096,1024] ----------
// z = col>>10: 0=q(+rope,*0.125*gamma^(s&63)), 1=k(+rope,*gamma^-(s&63), +kT),
// 2=v(->vT transposed), 3=g(silu)
__global__ __launch_bounds__(512, 2) void proj_kernel(
    const u16* __restrict__ xb, const u16* __restrict__ wcat,
    u16* __restrict__ qb, u16* __restrict__ kb, u16* __restrict__ kT,
    u16* __restrict__ vT, u16* __restrict__ gb,
    const float2* __restrict__ rope)
{
  __shared__ u16 lds[4 * (256 * 32 + 256 * 32)];   // 128 KB ring
  f32x4 acc[8][4];
  const int m0 = blockIdx.y * 256, n0 = blockIdx.x * 256;
  gemm_bk32<256, 256, 2, 4>(xb, wcat, m0, n0, lds, acc);

  const int lane = threadIdx.x & 63, wid = threadIdx.x >> 6;
  const int wm = wid >> 2, wn = wid & 3;
  const int l15 = lane & 15, l4 = lane >> 4;
  const int gcol = n0 + wn * 64;                   // wave = one head's 64 cols
  const int z  = gcol >> 10;
  const int hh = (gcol >> 6) & (NH - 1);
  const int mcol = gcol & (D_DIM - 1);
  const int rbase = m0 + wm * 128 + l4 * 4;
  const float lgh = log2f(1.f - exp2f(-5.f - (float)hh));   // log2(gamma_h) < 0

  if (z <= 1) {
    u16* dst = z ? kb : qb;
    const float slg  = z ? -lgh : lgh;
    const float base = z ? 1.f : 0.125f;
    #pragma unroll
    for (int m = 0; m < 8; ++m) {
      float o1v[2][4], o2v[2][4];
      #pragma unroll
      for (int r = 0; r < 4; ++r) {
        const int row = rbase + m * 16 + r;
        const int s = row & (S_LEN - 1);
        const float sc = base * exp2f((float)(s & 63) * slg);
        #pragma unroll
        for (int n = 0; n < 2; ++n) {
          const int dh0 = n * 16 + l15;            // 0..31
          const float2 cs = rope[s * 32 + dh0];
          const float x1 = acc[m][n][r], x2 = acc[m][n + 2][r];
          const float o1 = (x1 * cs.x - x2 * cs.y) * sc;
          const float o2 = (x2 * cs.x + x1 * cs.y) * sc;
          dst[(size_t)row * D_DIM + mcol + n * 16 + l15]       = f2bf(o1);
          dst[(size_t)row * D_DIM + mcol + (n + 2) * 16 + l15] = f2bf(o2);
          o1v[n][r] = o1; o2v[n][r] = o2;
        }
      }
      if (z == 1) {
        const int row0 = rbase + m * 16;
        const int bb = row0 >> 11, sr = row0 & (S_LEN - 1);
        #pragma unroll
        for (int n = 0; n < 2; ++n) {
          const int dh0 = n * 16 + l15;
          const uint2 p1 = make_uint2(pack_bf2(o1v[n][0], o1v[n][1]), pack_bf2(o1v[n][2], o1v[n][3]));
          const uint2 p2 = make_uint2(pack_bf2(o2v[n][0], o2v[n][1]), pack_bf2(o2v[n][2], o2v[n][3]));
          *(uint2*)(kT + (size_t)((bb * NH + hh) * DH + dh0) * S_LEN + sr)      = p1;
          *(uint2*)(kT + (size_t)((bb * NH + hh) * DH + dh0 + 32) * S_LEN + sr) = p2;
        }
      }
    }
  } else if (z == 2) {
    #pragma unroll
    for (int m = 0; m < 8; ++m) {
      const int row0 = rbase + m * 16;
      const int bb = row0 >> 11, sr = row0 & (S_LEN - 1);
      #pragma unroll
      for (int n = 0; n < 4; ++n) {
        const int dh = n * 16 + l15;
        const uint2 p = make_uint2(pack_bf2(acc[m][n][0], acc[m][n][1]),
                                   pack_bf2(acc[m][n][2], acc[m][n][3]));
        *(uint2*)(vT + (size_t)((bb * NH + hh) * DH + dh) * S_LEN + sr) = p;
      }
    }
  } else {
    #pragma unroll
    for (int m = 0; m < 8; ++m)
      #pragma unroll
      for (int n = 0; n < 4; ++n)
        #pragma unroll
        for (int r = 0; r < 4; ++r) {
          const int row = rbase + m * 16 + r;
          const float v = acc[m][n][r];
          gb[(size_t)row * D_DIM + mcol + n * 16 + l15] = f2bf(v / (1.f + __expf(-v)));
        }
  }
}

// ---------- phase A: per-chunk outer product  At[bh][c][d2][d1] = (K-hat^T V)^T ----------
__global__ __launch_bounds__(256) void chunk_accum(
    const u16* __restrict__ kT, const u16* __restrict__ vT,
    u16* __restrict__ At)
{
  const int tid = threadIdx.x, lane = tid & 63, w = tid >> 6;
  const int l15 = lane & 15, l4 = lane >> 4;
  const int bh = blockIdx.x >> 5, c = blockIdx.x & 31;

  short8 a[2], bfr[2][4];
  #pragma unroll
  for (int kk = 0; kk < 2; ++kk) {
    a[kk] = *(const short8*)(vT + (size_t)(bh * DH + w * 16 + l15) * S_LEN + c * 64 + kk * 32 + l4 * 8);
    #pragma unroll
    for (int n = 0; n < 4; ++n)
      bfr[kk][n] = *(const short8*)(kT + (size_t)(bh * DH + n * 16 + l15) * S_LEN + c * 64 + kk * 32 + l4 * 8);
  }
  f32x4 acc[4];
  #pragma unroll
  for (int n = 0; n < 4; ++n) acc[n] = (f32x4){0.f, 0.f, 0.f, 0.f};
  #pragma unroll
  for (int kk = 0; kk < 2; ++kk)
    #pragma unroll
    for (int n = 0; n < 4; ++n)
      acc[n] = __builtin_amdgcn_mfma_f32_16x16x32_bf16(a[kk], bfr[kk][n], acc[n], 0, 0, 0);

  u16* dst = At + ((size_t)(bh * NCHUNK + c)) * 4096;
  #pragma unroll
  for (int n = 0; n < 4; ++n)
    #pragma unroll
    for (int r = 0; r < 4; ++r)
      dst[(w * 16 + l4 * 4 + r) * 64 + n * 16 + l15] = f2bf(acc[n][r]);
}

// ---------- phase B: elementwise scan over chunks ----------
__global__ __launch_bounds__(256) void chunk_scan(
    const u16* __restrict__ At, u16* __restrict__ St)
{
  const int gid = blockIdx.x * 256 + threadIdx.x;   // 32 bh * 4096 elems
  const int bh = gid >> 12, e = gid & 4095;
  const int h = bh & (NH - 1);
  const float lg = log2f(1.f - exp2f(-5.f - (float)h));
  const float gC = exp2f(64.f * lg);
  const u16* src = At + (size_t)bh * NCHUNK * 4096 + e;
  u16* dst = St + (size_t)bh * NCHUNK * 4096 + e;
  float s = 0.f;
  for (int c = 0; c < NCHUNK; ++c) {
    const float a = bf2f(src[(size_t)c * 4096]);
    dst[(size_t)c * 4096] = f2bf(s);
    s = gC * (s + a);
  }
}

// ---------- phase C: O = (masked Q~K^^T) V + Q~ State, fused * g ----------
__global__ __launch_bounds__(256) void chunk_out(
    const u16* __restrict__ qb, const u16* __restrict__ kb,
    const u16* __restrict__ vT, const u16* __restrict__ St,
    const u16* __restrict__ gb, u16* __restrict__ ob)
{
  __shared__ u16 Ps[4][16 * 64];   // 2 KB per wave, XOR-swizzled

  const int tid = threadIdx.x, lane = tid & 63, w = tid >> 6;
  const int l15 = lane & 15, l4 = lane >> 4;
  const int bh = blockIdx.x >> 5, c = blockIdx.x & 31;
  const int b = bh >> 4, h = bh & (NH - 1);
  const int q0 = c * 64 + w * 16;

  short8 qfr[2], kf[2][4], vf[2][4], sf[2][4];
  #pragma unroll
  for (int kk = 0; kk < 2; ++kk) {
    qfr[kk] = *(const short8*)(qb + (size_t)(b * S_LEN + q0 + l15) * D_DIM + h * DH + kk * 32 + l4 * 8);
    #pragma unroll
    for (int t = 0; t < 4; ++t)
      kf[kk][t] = *(const short8*)(kb + (size_t)(b * S_LEN + c * 64 + t * 16 + l15) * D_DIM + h * DH + kk * 32 + l4 * 8);
    #pragma unroll
    for (int n = 0; n < 4; ++n) {
      vf[kk][n] = *(const short8*)(vT + (size_t)(bh * DH + n * 16 + l15) * S_LEN + c * 64 + kk * 32 + l4 * 8);
      sf[kk][n] = *(const short8*)(St + ((size_t)(bh * NCHUNK + c)) * 4096 + (n * 16 + l15) * 64 + kk * 32 + l4 * 8);
    }
  }

  // S^T = mfma(K^, Q~)
  f32x4 st[4];
  #pragma unroll
  for (int tf = 0; tf < 4; ++tf) st[tf] = (f32x4){0.f, 0.f, 0.f, 0.f};
  #pragma unroll
  for (int kk = 0; kk < 2; ++kk)
    #pragma unroll
    for (int tf = 0; tf < 4; ++tf)
      st[tf] = __builtin_amdgcn_mfma_f32_16x16x32_bf16(kf[kk][tf], qfr[kk], st[tf], 0, 0, 0);

  // cross term: acc = Q~ StateT
  f32x4 acc[4];
  #pragma unroll
  for (int n = 0; n < 4; ++n) acc[n] = (f32x4){0.f, 0.f, 0.f, 0.f};
  #pragma unroll
  for (int kk = 0; kk < 2; ++kk)
    #pragma unroll
    for (int n = 0; n < 4; ++n)
      acc[n] = __builtin_amdgcn_mfma_f32_16x16x32_bf16(qfr[kk], sf[kk][n], acc[n], 0, 0, 0);

  // mask (t' <= q'), pack, swizzled per-wave LDS write
  u16* const psw = &Ps[w][0];
  const int qq = w * 16 + l15;
  #pragma unroll
  for (int tf = 0; tf < 4; ++tf) {
    const int tb = tf * 16 + l4 * 4;
    const float v0 = (tb + 0 <= qq) ? st[tf][0] : 0.f;
    const float v1 = (tb + 1 <= qq) ? st[tf][1] : 0.f;
    const float v2 = (tb + 2 <= qq) ? st[tf][2] : 0.f;
    const float v3 = (tb + 3 <= qq) ? st[tf][3] : 0.f;
    const uint2 u = make_uint2(pack_bf2(v0, v1), pack_bf2(v2, v3));
    const int boff = l15 * 128 + ((tf * 32 + l4 * 8) ^ ((l15 & 7) << 4));
    *(uint2*)((char*)psw + boff) = u;
  }

  // O += P V
  #pragma unroll
  for (int kk = 0; kk < 2; ++kk) {
    const int boff = l15 * 128 + ((kk * 64 + l4 * 16) ^ ((l15 & 7) << 4));
    const short8 pa = *(const short8*)((const char*)psw + boff);
    #pragma unroll
    for (int n = 0; n < 4; ++n)
      acc[n] = __builtin_amdgcn_mfma_f32_16x16x32_bf16(pa, vf[kk][n], acc[n], 0, 0, 0);
  }

  #pragma unroll
  for (int n = 0; n < 4; ++n)
    #pragma unroll
    for (int r = 0; r < 4; ++r) {
      const size_t idx = (size_t)(b * S_LEN + q0 + l4 * 4 + r) * D_DIM + h * DH + n * 16 + l15;
      ob[idx] = f2bf(acc[n][r] * bf2f(gb[idx]));
    }
}

// ---------- final GEMM: out = (O .* g) @ wo^T, fp32 output ----------
__global__ __launch_bounds__(256, 2) void final_kernel(
    const u16* __restrict__ ob, const u16* __restrict__ wob,
    float* __restrict__ out)
{
  __shared__ u16 lds[4 * (128 * 32 + 128 * 32)];   // 64 KB ring
  f32x4 acc[4][4];
  const int m0 = blockIdx.y * 128, n0 = blockIdx.x * 128;
  gemm_bk32<128, 128, 2, 2>(ob, wob, m0, n0, lds, acc);

  const int lane = threadIdx.x & 63, wid = threadIdx.x >> 6;
  const int wm = wid >> 1, wn = wid & 1;
  const int rbase = m0 + wm * 64 + (lane >> 4) * 4;
  const int cbase = n0 + wn * 64 + (lane & 15);
  #pragma unroll
  for (int m = 0; m < 4; ++m)
    #pragma unroll
    for (int n = 0; n < 4; ++n)
      #pragma unroll
      for (int r = 0; r < 4; ++r)
        out[(size_t)(rbase + m * 16 + r) * D_DIM + cbase + n * 16] = acc[m][n][r];
}

extern "C" void kernel_launch(void* const* d_in, const int* in_sizes, int n_in,
                              void* d_out, int out_size, void* d_ws, size_t ws_size,
                              hipStream_t stream) {
  (void)in_sizes; (void)n_in; (void)out_size; (void)ws_size;
  const float* x  = (const float*)d_in[0];
  const float* wq = (const float*)d_in[1];
  const float* wk = (const float*)d_in[2];
  const float* wv = (const float*)d_in[3];
  const float* wg = (const float*)d_in[4];
  const float* wo = (const float*)d_in[5];
  float* out = (float*)d_out;

  char* ws = (char*)d_ws;
  const size_t SZ_X = (size_t)M_ROWS * D_DIM * 2;   // 8 MB
  const size_t SZ_W = (size_t)D_DIM * D_DIM * 2;    // 2 MB
  // [0..8)   xb            -> St  (state scan, alias after proj)
  // [8..16)  wqb..wgb=wcat -> At  (chunk products, alias after proj)
  // [16..18) wob           (live until final_kernel)
  // [18..26) qb  [26..34) kb  [34..42) vT  [42..50) gb
  // [50..58) kT            -> ob  (kT dead after chunk_accum)
  // [58..58.5) rope
  u16* xb   = (u16*)(ws);
  u16* wcat = (u16*)(ws + SZ_X);                    // wq,wk,wv,wg,(wo) contiguous
  u16* wob  = (u16*)(ws + SZ_X + 4 * SZ_W);
  u16* qb   = (u16*)(ws + 1 * SZ_X + 5 * SZ_W);
  u16* kb   = (u16*)(ws + 2 * SZ_X + 5 * SZ_W);
  u16* vT   = (u16*)(ws + 3 * SZ_X + 5 * SZ_W);
  u16* gb   = (u16*)(ws + 4 * SZ_X + 5 * SZ_W);
  u16* kT   = (u16*)(ws + 5 * SZ_X + 5 * SZ_W);
  u16* ob   = kT;                                   // alias: kT dead after chunk_accum
  float2* rope = (float2*)(ws + 6 * SZ_X + 5 * SZ_W);
  u16* St   = (u16*)(ws);                           // alias: xb dead after proj
  u16* At   = (u16*)(ws + SZ_X);                    // alias: wcat dead after proj

  const int nx4 = M_ROWS * D_DIM / 4;
  const int nw4 = D_DIM * D_DIM / 4;
  cvt_bf16<<<nx4 / 256, 256, 0, stream>>>(x, xb, nx4);
  cvt_w5<<<dim3(nw4 / 256, 5), 256, 0, stream>>>(wq, wk, wv, wg, wo, wcat);
  rope_tab<<<(S_LEN * 32) / 256, 256, 0, stream>>>(rope);

  proj_kernel<<<dim3(16, 16), 512, 0, stream>>>(xb, wcat, qb, kb, kT, vT, gb, rope);

  chunk_accum<<<dim3(B_SZ * NH * NCHUNK), 256, 0, stream>>>(kT, vT, At);
  chunk_scan<<<dim3(B_SZ * NH * 4096 / 256), 256, 0, stream>>>(At, St);
  chunk_out<<<dim3(B_SZ * NH * NCHUNK), 256, 0, stream>>>(qb, kb, vT, St, gb, ob);

  final_kernel<<<dim3(D_DIM / 128, M_ROWS / 128), 256, 0, stream>>>(ob, wob, out);
}

// Round 6
// 102.533 us; speedup vs baseline: 2.0878x; 1.0745x over previous
//
#include <hip/hip_runtime.h>
#include <hip/hip_bf16.h>

typedef unsigned short u16;
typedef unsigned int u32;
typedef __attribute__((ext_vector_type(8))) short short8;
typedef __attribute__((ext_vector_type(4))) float f32x4;

#define S_LEN 2048
#define D_DIM 1024
#define NH    16
#define DH    64
#define B_SZ  2
#define M_ROWS (B_SZ * S_LEN)   // 4096
#define NCHUNK (S_LEN / 64)     // 32 chunks of 64 rows

// ---------- helpers ----------
__device__ __forceinline__ u16 f2bf(float f) {
  u32 u = __float_as_uint(f);
  u += 0x7FFFu + ((u >> 16) & 1u);   // RNE
  return (u16)(u >> 16);
}
__device__ __forceinline__ float bf2f(u16 u) {
  return __uint_as_float(((u32)u) << 16);
}
__device__ __forceinline__ u32 pack_bf2(float lo, float hi) {
  __hip_bfloat162 p = __float22bfloat162_rn(make_float2(lo, hi));  // v_cvt_pk_bf16_f32
  u32 r;
  __builtin_memcpy(&r, &p, 4);
  return r;
}

__device__ __forceinline__ void gll16(const void* g, void* l) {
  __builtin_amdgcn_global_load_lds((const __attribute__((address_space(1))) u32*)g,
                                   (__attribute__((address_space(3))) u32*)l,
                                   16, 0, 0);
}

#define SP1() __builtin_amdgcn_s_setprio(1)
#define SP0() __builtin_amdgcn_s_setprio(0)
#define BAR() __builtin_amdgcn_s_barrier()
#define LGKM0() do { asm volatile("s_waitcnt lgkmcnt(0)" ::: "memory"); \
                     __builtin_amdgcn_sched_barrier(0); } while (0)

// ---------- fused prep: x->bf16, 5 weights->wcat bf16, rope table ----------
__global__ __launch_bounds__(256) void prep_kernel(
    const float* __restrict__ x,
    const float* __restrict__ wq, const float* __restrict__ wk,
    const float* __restrict__ wv, const float* __restrict__ wg,
    const float* __restrict__ wo,
    u16* __restrict__ xb, u16* __restrict__ wcat, float2* __restrict__ rope)
{
  const int bid = blockIdx.x, tid = threadIdx.x;
  if (bid < 4096) {                      // x: 4096*1024 elems / 4 = 1048576 float4
    const int i = bid * 256 + tid;
    const float4 v = ((const float4*)x)[i];
    u32* d = (u32*)xb;
    d[2 * i]     = (u32)f2bf(v.x) | ((u32)f2bf(v.y) << 16);
    d[2 * i + 1] = (u32)f2bf(v.z) | ((u32)f2bf(v.w) << 16);
  } else if (bid < 9216) {               // 5 weights, 1024 blocks each
    const int t = bid - 4096;
    const int seg = t >> 10;
    const float* src = seg == 0 ? wq : seg == 1 ? wk : seg == 2 ? wv : seg == 3 ? wg : wo;
    const int i = (t & 1023) * 256 + tid;
    const float4 v = ((const float4*)src)[i];
    u32* d = (u32*)(wcat + (size_t)seg * D_DIM * D_DIM);
    d[2 * i]     = (u32)f2bf(v.x) | ((u32)f2bf(v.y) << 16);
    d[2 * i + 1] = (u32)f2bf(v.z) | ((u32)f2bf(v.w) << 16);
  } else {                               // rope: S_LEN*32 entries, 256 blocks
    const int i = (bid - 9216) * 256 + tid;
    const int s = i >> 5, j = i & 31;
    float inv = exp2f(-(float)j * (13.287712379549449f / 32.f)); // 10000^(-j/32)
    float fr = (float)s * inv;
    rope[i] = make_float2(cosf(fr), sinf(fr));
  }
}

// ---------- 8-phase 256x256 proj GEMM + fused epilogues ----------
// z = col>>10: 0=q(+rope,*0.125*gamma^(s&63)), 1=k(+rope,*gamma^-(s&63), +kT),
// 2=v(->vT transposed), 3=g(silu)
__global__ __launch_bounds__(512, 2) void proj_kernel(
    const u16* __restrict__ xb, const u16* __restrict__ wcat,
    u16* __restrict__ qb, u16* __restrict__ kb, u16* __restrict__ kT,
    u16* __restrict__ vT, u16* __restrict__ gb,
    const float2* __restrict__ rope)
{
  // 128 KB: A halves [buf][h] at ((buf*2+h)*8192), B at 32768 + same
  __shared__ u16 lds[65536];
  const int tid = threadIdx.x, lane = tid & 63, wid = tid >> 6;
  const int wm = wid >> 2, wn = wid & 3;
  const int l15 = lane & 15, l4 = lane >> 4;

  const int bid = blockIdx.x;                     // 256 blocks, 256%8==0
  const int sw = (bid & 7) * 32 + (bid >> 3);     // XCD-bijective swizzle
  const int m0 = (sw & 15) * 256;
  const int n0 = (sw >> 4) * 256;

  f32x4 acc[8][4];
  #pragma unroll
  for (int m = 0; m < 8; ++m)
    #pragma unroll
    for (int n = 0; n < 4; ++n)
      acc[m][n] = (f32x4){0.f, 0.f, 0.f, 0.f};

  short8 a[4][2], b0[2][2], b1[2][2];

  // stage one half-tile (128 rows x 64 k-cols): 2 gll16 per thread,
  // pre-swizzled global source + linear LDS (rule 21)
  auto stA = [&](int t, int h) {
    u16* dst = lds + ((t & 1) * 2 + h) * 8192;
    const u16* src = xb + (size_t)(m0 + h * 128) * D_DIM + t * 64;
    #pragma unroll
    for (int j = 0; j < 2; ++j) {
      const int c = tid + j * 512, row = c >> 3, ch = c & 7;
      gll16(src + (size_t)row * D_DIM + ((ch ^ (row & 7)) << 3), dst + c * 8);
    }
  };
  auto stB = [&](int t, int h) {
    u16* dst = lds + 32768 + ((t & 1) * 2 + h) * 8192;
    const u16* src = wcat + (size_t)(n0 + h * 128) * D_DIM + t * 64;
    #pragma unroll
    for (int j = 0; j < 2; ++j) {
      const int c = tid + j * 512, row = c >> 3, ch = c & 7;
      gll16(src + (size_t)row * D_DIM + ((ch ^ (row & 7)) << 3), dst + c * 8);
    }
  };
  // fragment loads (swizzled read side)
  auto ldA = [&](int d, int mh) {
    const u16* base = lds + (d * 2 + wm) * 8192;
    #pragma unroll
    for (int m = 0; m < 4; ++m) {
      const int lr = mh * 64 + m * 16 + l15;
      #pragma unroll
      for (int kk = 0; kk < 2; ++kk)
        a[m][kk] = *(const short8*)(base + lr * 64 + (((kk * 4 + l4) ^ (lr & 7)) << 3));
    }
  };
  auto ldB = [&](short8 (&b)[2][2], int d, int nh) {
    const u16* base = lds + 32768 + (d * 2 + (wn >> 1)) * 8192;
    #pragma unroll
    for (int j = 0; j < 2; ++j) {
      const int lr = (wn & 1) * 64 + (nh * 2 + j) * 16 + l15;
      #pragma unroll
      for (int kk = 0; kk < 2; ++kk)
        b[j][kk] = *(const short8*)(base + lr * 64 + (((kk * 4 + l4) ^ (lr & 7)) << 3));
    }
  };
  auto quad = [&](int mh, int nh, short8 (&b)[2][2]) {
    #pragma unroll
    for (int m = 0; m < 4; ++m)
      #pragma unroll
      for (int j = 0; j < 2; ++j)
        #pragma unroll
        for (int kk = 0; kk < 2; ++kk)
          acc[mh * 4 + m][nh * 2 + j] =
              __builtin_amdgcn_mfma_f32_16x16x32_bf16(a[m][kk], b[j][kk],
                                                      acc[mh * 4 + m][nh * 2 + j], 0, 0, 0);
  };

  // prologue: tile0 (all 4 halves) + B(1,h0/h1); A(1,*) staged at iter0 p0/p1
  stB(0, 0); stA(0, 0); stB(0, 1); stA(0, 1); stB(1, 0); stB(1, 1);
  asm volatile("s_waitcnt vmcnt(4)" ::: "memory");   // tile0's 4 halves landed
  BAR();

  for (int i = 0; i < 8; ++i) {
    const int t1 = 2 * i + 1, t2 = 2 * i + 2, t3 = 2 * i + 3;
    // ---- P0: tile 2i (buf0), quad(0,0) ----
    ldA(0, 0); ldB(b0, 0, 0);
    stA(t1, 0);
    asm volatile("s_waitcnt lgkmcnt(8)" ::: "memory");
    BAR(); LGKM0();
    SP1(); quad(0, 0, b0); SP0();
    BAR();
    // ---- P1: quad(0,1) ----
    ldB(b1, 0, 1);
    stA(t1, 1);
    BAR(); LGKM0();
    SP1(); quad(0, 1, b1); SP0();
    BAR();
    // ---- P2: quad(1,0) ----
    ldA(0, 1);
    if (t2 < 16) stB(t2, 0);
    BAR(); LGKM0();
    SP1(); quad(1, 0, b0); SP0();
    BAR();
    // ---- P3: quad(1,1), vmcnt gate for tile 2i+1 ----
    if (t2 < 16) stA(t2, 0);
    BAR(); LGKM0();
    SP1(); quad(1, 1, b1); SP0();
    if (i == 7) asm volatile("s_waitcnt vmcnt(0)" ::: "memory");
    else        asm volatile("s_waitcnt vmcnt(4)" ::: "memory");
    BAR();
    // ---- P4: tile 2i+1 (buf1), quad(0,0) ----
    ldA(1, 0); ldB(b0, 1, 0);
    if (t2 < 16) stB(t2, 1);
    asm volatile("s_waitcnt lgkmcnt(8)" ::: "memory");
    BAR(); LGKM0();
    SP1(); quad(0, 0, b0); SP0();
    BAR();
    // ---- P5: quad(0,1) ----
    ldB(b1, 1, 1);
    if (t2 < 16) stA(t2, 1);
    BAR(); LGKM0();
    SP1(); quad(0, 1, b1); SP0();
    BAR();
    // ---- P6: quad(1,0) ----
    ldA(1, 1);
    if (t3 < 16) stB(t3, 0);
    BAR(); LGKM0();
    SP1(); quad(1, 0, b0); SP0();
    BAR();
    // ---- P7: quad(1,1), vmcnt gate for tile 2i+2 ----
    if (t3 < 16) stB(t3, 1);
    BAR(); LGKM0();
    SP1(); quad(1, 1, b1); SP0();
    if (i < 7) asm volatile("s_waitcnt vmcnt(4)" ::: "memory");
    BAR();
  }

  // ---- epilogue: z-dispatched fused stores ----
  const int gcol = n0 + wn * 64;                 // wave = one head's 64 cols
  const int z = gcol >> 10;                      // block-uniform
  const int hh = (gcol >> 6) & (NH - 1);
  const int mcol = gcol & (D_DIM - 1);
  const int rbase = m0 + wm * 128 + l4 * 4;
  const float lgh = log2f(1.f - exp2f(-5.f - (float)hh));   // log2(gamma_h) < 0

  if (z <= 1) {
    u16* dst = z ? kb : qb;
    const float slg  = z ? -lgh : lgh;
    const float base = z ? 1.f : 0.125f;
    #pragma unroll
    for (int m = 0; m < 8; ++m) {
      float o1v[2][4], o2v[2][4];
      #pragma unroll
      for (int r = 0; r < 4; ++r) {
        const int row = rbase + m * 16 + r;
        const int s = row & (S_LEN - 1);
        const float sc = base * exp2f((float)(s & 63) * slg);
        #pragma unroll
        for (int n = 0; n < 2; ++n) {
          const int dh0 = n * 16 + l15;          // 0..31
          const float2 cs = rope[s * 32 + dh0];
          const float x1 = acc[m][n][r], x2 = acc[m][n + 2][r];
          const float o1 = (x1 * cs.x - x2 * cs.y) * sc;
          const float o2 = (x2 * cs.x + x1 * cs.y) * sc;
          dst[(size_t)row * D_DIM + mcol + n * 16 + l15]       = f2bf(o1);
          dst[(size_t)row * D_DIM + mcol + (n + 2) * 16 + l15] = f2bf(o2);
          o1v[n][r] = o1; o2v[n][r] = o2;
        }
      }
      if (z == 1) {
        const int row0 = rbase + m * 16;
        const int bb = row0 >> 11, sr = row0 & (S_LEN - 1);
        #pragma unroll
        for (int n = 0; n < 2; ++n) {
          const int dh0 = n * 16 + l15;
          const uint2 p1 = make_uint2(pack_bf2(o1v[n][0], o1v[n][1]), pack_bf2(o1v[n][2], o1v[n][3]));
          const uint2 p2 = make_uint2(pack_bf2(o2v[n][0], o2v[n][1]), pack_bf2(o2v[n][2], o2v[n][3]));
          *(uint2*)(kT + (size_t)((bb * NH + hh) * DH + dh0) * S_LEN + sr)      = p1;
          *(uint2*)(kT + (size_t)((bb * NH + hh) * DH + dh0 + 32) * S_LEN + sr) = p2;
        }
      }
    }
  } else if (z == 2) {
    #pragma unroll
    for (int m = 0; m < 8; ++m) {
      const int row0 = rbase + m * 16;
      const int bb = row0 >> 11, sr = row0 & (S_LEN - 1);
      #pragma unroll
      for (int n = 0; n < 4; ++n) {
        const int dh = n * 16 + l15;
        const uint2 p = make_uint2(pack_bf2(acc[m][n][0], acc[m][n][1]),
                                   pack_bf2(acc[m][n][2], acc[m][n][3]));
        *(uint2*)(vT + (size_t)((bb * NH + hh) * DH + dh) * S_LEN + sr) = p;
      }
    }
  } else {
    #pragma unroll
    for (int m = 0; m < 8; ++m)
      #pragma unroll
      for (int n = 0; n < 4; ++n)
        #pragma unroll
        for (int r = 0; r < 4; ++r) {
          const int row = rbase + m * 16 + r;
          const float v = acc[m][n][r];
          gb[(size_t)row * D_DIM + mcol + n * 16 + l15] = f2bf(v / (1.f + __expf(-v)));
        }
  }
}

// ---------- ring-4 BK32 GEMM core (final_kernel) ----------
template<int BM, int BN, int WPM, int WPN>
__device__ __forceinline__ void gemm_bk32(const u16* __restrict__ A,
                                          const u16* __restrict__ W,
                                          const int m0, const int n0,
                                          u16* lds,
                                          f32x4 (&acc)[BM / (WPM * 16)][BN / (WPN * 16)])
{
  constexpr int T   = WPM * WPN * 64;
  constexpr int MR  = BM / (WPM * 16);
  constexpr int NR  = BN / (WPN * 16);
  constexpr int ALD = BM * 32;
  constexpr int BLD = BN * 32;
  constexpr int BUF = ALD + BLD;
  constexpr int NK  = D_DIM / 32;

  const int tid  = threadIdx.x;
  const int lane = tid & 63, wid = tid >> 6;
  const int wm = wid / WPN, wn = wid % WPN;
  const int l15 = lane & 15, l4 = lane >> 4;

  #pragma unroll
  for (int m = 0; m < MR; ++m)
    #pragma unroll
    for (int n = 0; n < NR; ++n)
      acc[m][n] = (f32x4){0.f, 0.f, 0.f, 0.f};

  auto stage = [&](int kt) {
    const int k0 = kt * 32;
    u16* la = lds + (kt & 3) * BUF;
    u16* lb = la + ALD;
    #pragma unroll
    for (int j = 0; j < BM * 4 / T; ++j) {
      const int c = tid + j * T;
      gll16(A + (size_t)(m0 + (c >> 2)) * D_DIM + k0 + (c & 3) * 8, la + c * 8);
    }
    #pragma unroll
    for (int j = 0; j < BN * 4 / T; ++j) {
      const int c = tid + j * T;
      gll16(W + (size_t)(n0 + (c >> 2)) * D_DIM + k0 + (c & 3) * 8, lb + c * 8);
    }
  };

  stage(0);
  stage(1);
  asm volatile("s_waitcnt vmcnt(4)" ::: "memory");
  BAR();
  __builtin_amdgcn_sched_barrier(0);

  for (int i = 0; i < NK; ++i) {
    if (i + 2 < NK) stage(i + 2);
    const u16* la = lds + (i & 3) * BUF + (wm * (BM / WPM) + l15) * 32 + l4 * 8;
    const u16* lb = lds + (i & 3) * BUF + ALD + (wn * (BN / WPN) + l15) * 32 + l4 * 8;
    short8 av[MR], bv[NR];
    #pragma unroll
    for (int m = 0; m < MR; ++m) av[m] = *(const short8*)(la + m * 16 * 32);
    #pragma unroll
    for (int n = 0; n < NR; ++n) bv[n] = *(const short8*)(lb + n * 16 * 32);
    SP1();
    #pragma unroll
    for (int m = 0; m < MR; ++m)
      #pragma unroll
      for (int n = 0; n < NR; ++n)
        acc[m][n] = __builtin_amdgcn_mfma_f32_16x16x32_bf16(av[m], bv[n], acc[m][n], 0, 0, 0);
    SP0();
    if (i + 2 < NK) asm volatile("s_waitcnt vmcnt(4)" ::: "memory");
    else            asm volatile("s_waitcnt vmcnt(0)" ::: "memory");
    BAR();
    __builtin_amdgcn_sched_barrier(0);
  }
}

// ---------- phase A: per-chunk outer product  At[bh][c][d2][d1] = (K-hat^T V)^T ----------
__global__ __launch_bounds__(256) void chunk_accum(
    const u16* __restrict__ kT, const u16* __restrict__ vT,
    u16* __restrict__ At)
{
  const int tid = threadIdx.x, lane = tid & 63, w = tid >> 6;
  const int l15 = lane & 15, l4 = lane >> 4;
  const int bh = blockIdx.x >> 5, c = blockIdx.x & 31;

  short8 a[2], bfr[2][4];
  #pragma unroll
  for (int kk = 0; kk < 2; ++kk) {
    a[kk] = *(const short8*)(vT + (size_t)(bh * DH + w * 16 + l15) * S_LEN + c * 64 + kk * 32 + l4 * 8);
    #pragma unroll
    for (int n = 0; n < 4; ++n)
      bfr[kk][n] = *(const short8*)(kT + (size_t)(bh * DH + n * 16 + l15) * S_LEN + c * 64 + kk * 32 + l4 * 8);
  }
  f32x4 acc[4];
  #pragma unroll
  for (int n = 0; n < 4; ++n) acc[n] = (f32x4){0.f, 0.f, 0.f, 0.f};
  #pragma unroll
  for (int kk = 0; kk < 2; ++kk)
    #pragma unroll
    for (int n = 0; n < 4; ++n)
      acc[n] = __builtin_amdgcn_mfma_f32_16x16x32_bf16(a[kk], bfr[kk][n], acc[n], 0, 0, 0);

  u16* dst = At + ((size_t)(bh * NCHUNK + c)) * 4096;
  #pragma unroll
  for (int n = 0; n < 4; ++n)
    #pragma unroll
    for (int r = 0; r < 4; ++r)
      dst[(w * 16 + l4 * 4 + r) * 64 + n * 16 + l15] = f2bf(acc[n][r]);
}

// ---------- phase B: elementwise scan over chunks ----------
__global__ __launch_bounds__(256) void chunk_scan(
    const u16* __restrict__ At, u16* __restrict__ St)
{
  const int gid = blockIdx.x * 256 + threadIdx.x;   // 32 bh * 4096 elems
  const int bh = gid >> 12, e = gid & 4095;
  const int h = bh & (NH - 1);
  const float lg = log2f(1.f - exp2f(-5.f - (float)h));
  const float gC = exp2f(64.f * lg);
  const u16* src = At + (size_t)bh * NCHUNK * 4096 + e;
  u16* dst = St + (size_t)bh * NCHUNK * 4096 + e;
  float s = 0.f;
  for (int c = 0; c < NCHUNK; ++c) {
    const float a = bf2f(src[(size_t)c * 4096]);
    dst[(size_t)c * 4096] = f2bf(s);
    s = gC * (s + a);
  }
}

// ---------- phase C: O = (masked Q~K^^T) V + Q~ State, fused * g ----------
__global__ __launch_bounds__(256) void chunk_out(
    const u16* __restrict__ qb, const u16* __restrict__ kb,
    const u16* __restrict__ vT, const u16* __restrict__ St,
    const u16* __restrict__ gb, u16* __restrict__ ob)
{
  __shared__ u16 Ps[4][16 * 64];   // 2 KB per wave, XOR-swizzled

  const int tid = threadIdx.x, lane = tid & 63, w = tid >> 6;
  const int l15 = lane & 15, l4 = lane >> 4;
  const int bh = blockIdx.x >> 5, c = blockIdx.x & 31;
  const int b = bh >> 4, h = bh & (NH - 1);
  const int q0 = c * 64 + w * 16;

  short8 qfr[2], kf[2][4], vf[2][4], sf[2][4];
  #pragma unroll
  for (int kk = 0; kk < 2; ++kk) {
    qfr[kk] = *(const short8*)(qb + (size_t)(b * S_LEN + q0 + l15) * D_DIM + h * DH + kk * 32 + l4 * 8);
    #pragma unroll
    for (int t = 0; t < 4; ++t)
      kf[kk][t] = *(const short8*)(kb + (size_t)(b * S_LEN + c * 64 + t * 16 + l15) * D_DIM + h * DH + kk * 32 + l4 * 8);
    #pragma unroll
    for (int n = 0; n < 4; ++n) {
      vf[kk][n] = *(const short8*)(vT + (size_t)(bh * DH + n * 16 + l15) * S_LEN + c * 64 + kk * 32 + l4 * 8);
      sf[kk][n] = *(const short8*)(St + ((size_t)(bh * NCHUNK + c)) * 4096 + (n * 16 + l15) * 64 + kk * 32 + l4 * 8);
    }
  }

  // S^T = mfma(K^, Q~)
  f32x4 st[4];
  #pragma unroll
  for (int tf = 0; tf < 4; ++tf) st[tf] = (f32x4){0.f, 0.f, 0.f, 0.f};
  #pragma unroll
  for (int kk = 0; kk < 2; ++kk)
    #pragma unroll
    for (int tf = 0; tf < 4; ++tf)
      st[tf] = __builtin_amdgcn_mfma_f32_16x16x32_bf16(kf[kk][tf], qfr[kk], st[tf], 0, 0, 0);

  // cross term: acc = Q~ StateT
  f32x4 acc[4];
  #pragma unroll
  for (int n = 0; n < 4; ++n) acc[n] = (f32x4){0.f, 0.f, 0.f, 0.f};
  #pragma unroll
  for (int kk = 0; kk < 2; ++kk)
    #pragma unroll
    for (int n = 0; n < 4; ++n)
      acc[n] = __builtin_amdgcn_mfma_f32_16x16x32_bf16(qfr[kk], sf[kk][n], acc[n], 0, 0, 0);

  // mask (t' <= q'), pack, swizzled per-wave LDS write
  u16* const psw = &Ps[w][0];
  const int qq = w * 16 + l15;
  #pragma unroll
  for (int tf = 0; tf < 4; ++tf) {
    const int tb = tf * 16 + l4 * 4;
    const float v0 = (tb + 0 <= qq) ? st[tf][0] : 0.f;
    const float v1 = (tb + 1 <= qq) ? st[tf][1] : 0.f;
    const float v2 = (tb + 2 <= qq) ? st[tf][2] : 0.f;
    const float v3 = (tb + 3 <= qq) ? st[tf][3] : 0.f;
    const uint2 u = make_uint2(pack_bf2(v0, v1), pack_bf2(v2, v3));
    const int boff = l15 * 128 + ((tf * 32 + l4 * 8) ^ ((l15 & 7) << 4));
    *(uint2*)((char*)psw + boff) = u;
  }

  // O += P V
  #pragma unroll
  for (int kk = 0; kk < 2; ++kk) {
    const int boff = l15 * 128 + ((kk * 64 + l4 * 16) ^ ((l15 & 7) << 4));
    const short8 pa = *(const short8*)((const char*)psw + boff);
    #pragma unroll
    for (int n = 0; n < 4; ++n)
      acc[n] = __builtin_amdgcn_mfma_f32_16x16x32_bf16(pa, vf[kk][n], acc[n], 0, 0, 0);
  }

  #pragma unroll
  for (int n = 0; n < 4; ++n)
    #pragma unroll
    for (int r = 0; r < 4; ++r) {
      const size_t idx = (size_t)(b * S_LEN + q0 + l4 * 4 + r) * D_DIM + h * DH + n * 16 + l15;
      ob[idx] = f2bf(acc[n][r] * bf2f(gb[idx]));
    }
}

// ---------- final GEMM: out = (O .* g) @ wo^T, fp32 output ----------
__global__ __launch_bounds__(256, 2) void final_kernel(
    const u16* __restrict__ ob, const u16* __restrict__ wob,
    float* __restrict__ out)
{
  __shared__ u16 lds[4 * (128 * 32 + 128 * 32)];   // 64 KB ring
  f32x4 acc[4][4];
  const int bid = blockIdx.x;                      // 256 blocks
  const int sw = (bid & 7) * 32 + (bid >> 3);      // XCD swizzle
  const int n0 = (sw & 7) * 128;
  const int m0 = (sw >> 3) * 128;
  gemm_bk32<128, 128, 2, 2>(ob, wob, m0, n0, lds, acc);

  const int lane = threadIdx.x & 63, wid = threadIdx.x >> 6;
  const int wm = wid >> 1, wn = wid & 1;
  const int rbase = m0 + wm * 64 + (lane >> 4) * 4;
  const int cbase = n0 + wn * 64 + (lane & 15);
  #pragma unroll
  for (int m = 0; m < 4; ++m)
    #pragma unroll
    for (int n = 0; n < 4; ++n)
      #pragma unroll
      for (int r = 0; r < 4; ++r)
        out[(size_t)(rbase + m * 16 + r) * D_DIM + cbase + n * 16] = acc[m][n][r];
}

extern "C" void kernel_launch(void* const* d_in, const int* in_sizes, int n_in,
                              void* d_out, int out_size, void* d_ws, size_t ws_size,
                              hipStream_t stream) {
  (void)in_sizes; (void)n_in; (void)out_size; (void)ws_size;
  const float* x  = (const float*)d_in[0];
  const float* wq = (const float*)d_in[1];
  const float* wk = (const float*)d_in[2];
  const float* wv = (const float*)d_in[3];
  const float* wg = (const float*)d_in[4];
  const float* wo = (const float*)d_in[5];
  float* out = (float*)d_out;

  char* ws = (char*)d_ws;
  const size_t SZ_X = (size_t)M_ROWS * D_DIM * 2;   // 8 MB
  const size_t SZ_W = (size_t)D_DIM * D_DIM * 2;    // 2 MB
  // [0..8)   xb            -> St  (state scan, alias after proj)
  // [8..16)  wcat[0..4)    -> At  (chunk products, alias after proj)
  // [16..18) wob = wcat[4] (live until final_kernel)
  // [18..26) qb  [26..34) kb  [34..42) vT  [42..50) gb
  // [50..58) kT            -> ob  (kT dead after chunk_accum)
  // [58..58.5) rope
  u16* xb   = (u16*)(ws);
  u16* wcat = (u16*)(ws + SZ_X);
  u16* wob  = (u16*)(ws + SZ_X + 4 * SZ_W);
  u16* qb   = (u16*)(ws + 1 * SZ_X + 5 * SZ_W);
  u16* kb   = (u16*)(ws + 2 * SZ_X + 5 * SZ_W);
  u16* vT   = (u16*)(ws + 3 * SZ_X + 5 * SZ_W);
  u16* gb   = (u16*)(ws + 4 * SZ_X + 5 * SZ_W);
  u16* kT   = (u16*)(ws + 5 * SZ_X + 5 * SZ_W);
  u16* ob   = kT;
  float2* rope = (float2*)(ws + 6 * SZ_X + 5 * SZ_W);
  u16* St   = (u16*)(ws);
  u16* At   = (u16*)(ws + SZ_X);

  prep_kernel<<<dim3(9472), 256, 0, stream>>>(x, wq, wk, wv, wg, wo, xb, wcat, rope);

  proj_kernel<<<dim3(256), 512, 0, stream>>>(xb, wcat, qb, kb, kT, vT, gb, rope);

  chunk_accum<<<dim3(B_SZ * NH * NCHUNK), 256, 0, stream>>>(kT, vT, At);
  chunk_scan<<<dim3(B_SZ * NH * 4096 / 256), 256, 0, stream>>>(At, St);
  chunk_out<<<dim3(B_SZ * NH * NCHUNK), 256, 0, stream>>>(qb, kb, vT, St, gb, ob);

  final_kernel<<<dim3(256), 256, 0, stream>>>(ob, wob, out);
}